// Round 1
// baseline (382.986 us; speedup 1.0000x reference)
//
#include <hip/hip_runtime.h>

typedef __bf16 bf16x8 __attribute__((ext_vector_type(8)));
typedef float f32x4 __attribute__((ext_vector_type(4)));
typedef unsigned short u16x8 __attribute__((ext_vector_type(8)));
typedef int i32x4 __attribute__((ext_vector_type(4)));

#define M_TOT 8192
#define K_TOT 4096
#define N_TOT 4096

__device__ __forceinline__ unsigned short f2bf(float f) {
  union { float f; unsigned int u; } v; v.f = f;
  unsigned int u = v.u;
  return (unsigned short)((u + 0x7FFFu + ((u >> 16) & 1u)) >> 16);  // RNE
}

// weight[o][i] = bf16(codebook[o, indices[o,i]]); one thread = 8 contiguous elems
__global__ __launch_bounds__(256) void deq_w(const float* __restrict__ cb,
                                             const int* __restrict__ idx,
                                             unsigned short* __restrict__ Wb) {
  size_t base = ((size_t)blockIdx.x * 256 + threadIdx.x) * 8;
  const float* crow = cb + ((base >> 12) << 8);  // row = base/4096, 256 floats/row
  i32x4 i0 = *(const i32x4*)(idx + base);
  i32x4 i1 = *(const i32x4*)(idx + base + 4);
  u16x8 o;
#pragma unroll
  for (int j = 0; j < 4; ++j) { o[j] = f2bf(crow[i0[j]]); o[4 + j] = f2bf(crow[i1[j]]); }
  *(u16x8*)(Wb + base) = o;
}

// x f32 -> bf16
__global__ __launch_bounds__(256) void conv_x(const float* __restrict__ X,
                                              unsigned short* __restrict__ Xc) {
  size_t base = ((size_t)blockIdx.x * 256 + threadIdx.x) * 8;
  f32x4 a = *(const f32x4*)(X + base);
  f32x4 b = *(const f32x4*)(X + base + 4);
  u16x8 o;
#pragma unroll
  for (int j = 0; j < 4; ++j) { o[j] = f2bf(a[j]); o[4 + j] = f2bf(b[j]); }
  *(u16x8*)(Xc + base) = o;
}

#define GLDS16(g, l)                                                      \
  __builtin_amdgcn_global_load_lds(                                       \
      (__attribute__((address_space(1))) void*)(g),                       \
      (__attribute__((address_space(3))) void*)(l), 16, 0, 0)

// C[M][N] = A[M][K] * B[N][K]^T + bias   (both operands k-contiguous bf16)
// 128x128 tile, BK=32, 4 waves (2x2), each wave 64x64 = 4x4 frags of 16x16x32.
__global__ __launch_bounds__(256) void gemm_bt(const unsigned short* __restrict__ A,
                                               const unsigned short* __restrict__ B,
                                               const float* __restrict__ bias,
                                               float* __restrict__ C) {
  __shared__ unsigned short Ash[128 * 32];
  __shared__ unsigned short Bsh[128 * 32];

  const int tid = threadIdx.x;
  const int lane = tid & 63;
  const int w = tid >> 6;
  const int wm = w >> 1, wn = w & 1;

  // bijective XCD swizzle: nwg = 2048 = 8 * 256
  const int bid = blockIdx.x;
  const int swz = (bid & 7) * 256 + (bid >> 3);
  const int bm = swz >> 5;   // 0..63  (M tiles)
  const int bn = swz & 31;   // 0..31  (N tiles)

  const size_t Abase = (size_t)bm * 128 * K_TOT;
  const size_t Bbase = (size_t)bn * 128 * K_TOT;

  f32x4 acc[4][4] = {};

  const int kc = (tid & 3) * 8;          // k-subchunk within row (8 bf16 = 16B)
  const int lr = lane & 15;
  const int kg = (lane >> 4) * 8;

  for (int kt = 0; kt < K_TOT; kt += 32) {
    // ---- stage A(128x32) and B(128x32) via global_load_lds, 16B/lane ----
#pragma unroll
    for (int it = 0; it < 2; ++it) {
      const int c = it * 256 + tid;      // chunk id: 4 chunks per row
      const int row = c >> 2;
      const unsigned short* gA = A + Abase + (size_t)row * K_TOT + kt + kc;
      const unsigned short* gB = B + Bbase + (size_t)row * K_TOT + kt + kc;
      // wave-uniform LDS base; HW adds lane*16B
      unsigned short* lA = &Ash[(it * 256 + (tid & 192)) * 8];
      unsigned short* lB = &Bsh[(it * 256 + (tid & 192)) * 8];
      GLDS16(gA, lA);
      GLDS16(gB, lB);
    }
    __syncthreads();  // compiler emits vmcnt(0) drain before s_barrier

    bf16x8 af[4], bfr[4];
#pragma unroll
    for (int mr = 0; mr < 4; ++mr)
      af[mr] = *(const bf16x8*)&Ash[(wm * 64 + mr * 16 + lr) * 32 + kg];
#pragma unroll
    for (int nr = 0; nr < 4; ++nr)
      bfr[nr] = *(const bf16x8*)&Bsh[(wn * 64 + nr * 16 + lr) * 32 + kg];

#pragma unroll
    for (int mr = 0; mr < 4; ++mr)
#pragma unroll
      for (int nr = 0; nr < 4; ++nr)
        acc[mr][nr] = __builtin_amdgcn_mfma_f32_16x16x32_bf16(af[mr], bfr[nr],
                                                              acc[mr][nr], 0, 0, 0);
    __syncthreads();
  }

  // ---- epilogue: C[row][col] = acc + bias[col] ----
  const int lg = lane >> 4;
#pragma unroll
  for (int nr = 0; nr < 4; ++nr) {
    const int col = bn * 128 + wn * 64 + nr * 16 + lr;
    const float bv = bias[col];
#pragma unroll
    for (int mr = 0; mr < 4; ++mr) {
      const int row0 = bm * 128 + wm * 64 + mr * 16 + lg * 4;
#pragma unroll
      for (int j = 0; j < 4; ++j)
        C[(size_t)(row0 + j) * N_TOT + col] = acc[mr][nr][j] + bv;
    }
  }
}

extern "C" void kernel_launch(void* const* d_in, const int* in_sizes, int n_in,
                              void* d_out, int out_size, void* d_ws, size_t ws_size,
                              hipStream_t stream) {
  const float* x    = (const float*)d_in[0];   // [4,2048,4096] f32
  const float* cb   = (const float*)d_in[1];   // [4096,256]   f32
  const float* bias = (const float*)d_in[2];   // [4096]       f32
  const int*   idx  = (const int*)d_in[3];     // [4096,4096]  int

  float* out = (float*)d_out;                  // [4,2048,4096] f32

  unsigned short* Wb = (unsigned short*)d_ws;                                  // 32 MB
  unsigned short* Xc = (unsigned short*)((char*)d_ws + (size_t)N_TOT * K_TOT * 2); // 64 MB

  // 16.7M weights / (8 per thread * 256) = 8192 blocks
  deq_w<<<(N_TOT * (size_t)K_TOT) / (8 * 256), 256, 0, stream>>>(cb, idx, Wb);
  // 33.5M x elems / 2048 = 16384 blocks
  conv_x<<<((size_t)M_TOT * K_TOT) / (8 * 256), 256, 0, stream>>>(x, Xc);
  // (8192/128) * (4096/128) = 64*32 = 2048 blocks
  gemm_bt<<<2048, 256, 0, stream>>>(Xc, Wb, bias, out);
}

// Round 2
// 288.401 us; speedup vs baseline: 1.3280x; 1.3280x over previous
//
#include <hip/hip_runtime.h>

typedef __bf16 bf16x8 __attribute__((ext_vector_type(8)));
typedef float f32x4 __attribute__((ext_vector_type(4)));
typedef unsigned short u16x8 __attribute__((ext_vector_type(8)));
typedef int i32x4 __attribute__((ext_vector_type(4)));

#define M_TOT 8192
#define K_TOT 4096
#define N_TOT 4096
#define BM 256
#define BN 256
#define BK 64
#define NT (K_TOT / BK)

__device__ __forceinline__ unsigned short f2bf(float f) {
  union { float f; unsigned int u; } v; v.f = f;
  unsigned int u = v.u;
  return (unsigned short)((u + 0x7FFFu + ((u >> 16) & 1u)) >> 16);  // RNE
}

// weight[o][i] = bf16(codebook[o, indices[o,i]]); one thread = 8 contiguous elems
__global__ __launch_bounds__(256) void deq_w(const float* __restrict__ cb,
                                             const int* __restrict__ idx,
                                             unsigned short* __restrict__ Wb) {
  size_t base = ((size_t)blockIdx.x * 256 + threadIdx.x) * 8;
  const float* crow = cb + ((base >> 12) << 8);  // row = base/4096, 256 floats/row
  i32x4 i0 = *(const i32x4*)(idx + base);
  i32x4 i1 = *(const i32x4*)(idx + base + 4);
  u16x8 o;
#pragma unroll
  for (int j = 0; j < 4; ++j) { o[j] = f2bf(crow[i0[j]]); o[4 + j] = f2bf(crow[i1[j]]); }
  *(u16x8*)(Wb + base) = o;
}

// x f32 -> bf16
__global__ __launch_bounds__(256) void conv_x(const float* __restrict__ X,
                                              unsigned short* __restrict__ Xc) {
  size_t base = ((size_t)blockIdx.x * 256 + threadIdx.x) * 8;
  f32x4 a = *(const f32x4*)(X + base);
  f32x4 b = *(const f32x4*)(X + base + 4);
  u16x8 o;
#pragma unroll
  for (int j = 0; j < 4; ++j) { o[j] = f2bf(a[j]); o[4 + j] = f2bf(b[j]); }
  *(u16x8*)(Xc + base) = o;
}

#define GLDS16(g, l)                                                      \
  __builtin_amdgcn_global_load_lds(                                       \
      (__attribute__((address_space(1))) void*)(g),                       \
      (__attribute__((address_space(3))) void*)(l), 16, 0, 0)

// ============================================================================
// 256x256 tile, BK=64, 8 waves (2M x 4N), double-buffered 128KB LDS,
// 4 phases per K-tile, counted vmcnt(4) at tile boundary, st-style XOR swizzle.
// LDS per buffer: A[256 rows][128B] at +0, B[256 rows][128B] at +32768.
// Swizzle: byte col ^= ((row&7)<<4); applied inverse on global src for staging.
// Staging schedule (group t): p0: A-h0(t+1)->other buf; p1: A-h1(t+1);
//                             p2: B-h0(t+2)->cur buf (B dead after p0);
//                             p3: B-h1(t+2); then vmcnt(4) [tail: 0]; barrier.
// ============================================================================
__global__ __launch_bounds__(512, 2) void gemm8(const unsigned short* __restrict__ A,
                                                const unsigned short* __restrict__ B,
                                                const float* __restrict__ bias,
                                                float* __restrict__ C) {
  __shared__ __attribute__((aligned(128))) char lds[131072];

  const int tid = threadIdx.x;
  const int lane = tid & 63;
  const int wm = (tid >> 6) >> 2;   // 0..1
  const int wn = (tid >> 6) & 3;    // 0..3
  const int lr = lane & 15;

  const int bid = blockIdx.x;                    // nwg = 512 = 8 * 64, bijective
  const int swz = (bid & 7) * 64 + (bid >> 3);
  const int bm = swz >> 4;                       // 0..31
  const int bn = swz & 15;                       // 0..15

  const unsigned short* Ap = A + (size_t)bm * BM * K_TOT;
  const unsigned short* Bp = B + (size_t)bn * BN * K_TOT;

  // staging constants: 512 thr x 16B = 64 rows/issue, 2 issues per 128-row half
  const int srow = tid >> 3;                              // 0..63
  const int sgcol = (((tid & 7) * 16) ^ ((srow & 7) << 4)) >> 1;  // global elem col (inv swizzle)
  const int wavebase = (tid & 448) << 4;                  // (tid>>6)*1024, wave-uniform

  // fragment-read constants (swizzled byte cols for ks=0/1)
  const int cs0 = (((lane >> 4) << 4)) ^ ((lr & 7) << 4);
  const int cs1 = (64 + ((lane >> 4) << 4)) ^ ((lr & 7) << 4);
  const int rowA0 = (wm * 128 + lr) * 128;          // byte base of A frags
  const int rowB0 = 32768 + (wn * 64 + lr) * 128;   // byte base of B frags

#define RD(off) (*(const bf16x8*)(lds + (off)))
#define STAGE(GB, TK, RB, LOFF)                                               \
  { _Pragma("unroll")                                                         \
    for (int ii = 0; ii < 2; ++ii) {                                          \
      GLDS16((GB) + (size_t)((RB) + ii * 64 + srow) * K_TOT + (TK) + sgcol,   \
             lds + (LOFF) + ii * 8192 + wavebase);                            \
    } }
#define BARRIER()                       \
  {                                     \
    asm volatile("" ::: "memory");      \
    __builtin_amdgcn_s_barrier();       \
    asm volatile("" ::: "memory");      \
  }
#define MFMA4(P, A0, A1, B0K, B1K)                                                     \
  {                                                                                    \
    _Pragma("unroll")                                                                  \
    for (int nf = 0; nf < 4; ++nf) {                                                   \
      acc[2*(P)][nf]   = __builtin_amdgcn_mfma_f32_16x16x32_bf16(A0, B0K[nf], acc[2*(P)][nf], 0, 0, 0);   \
      acc[2*(P)][nf]   = __builtin_amdgcn_mfma_f32_16x16x32_bf16(A1, B1K[nf], acc[2*(P)][nf], 0, 0, 0);   \
      acc[2*(P)+1][nf] = __builtin_amdgcn_mfma_f32_16x16x32_bf16(A0b, B0K[nf], acc[2*(P)+1][nf], 0, 0, 0);\
      acc[2*(P)+1][nf] = __builtin_amdgcn_mfma_f32_16x16x32_bf16(A1b, B1K[nf], acc[2*(P)+1][nf], 0, 0, 0);\
    }                                                                                  \
  }

  f32x4 acc[8][4] = {};

  // ---- prologue: tile0 (B,B,A,A) + tile1 (B,B); then t0 landed, t1.B in flight
  STAGE(Bp, 0, 0, 32768);
  STAGE(Bp, 0, 128, 49152);
  STAGE(Ap, 0, 0, 0);
  STAGE(Ap, 0, 128, 16384);
  STAGE(Bp, BK, 0, 65536 + 32768);
  STAGE(Bp, BK, 128, 65536 + 49152);
  asm volatile("s_waitcnt vmcnt(4)" ::: "memory");
  BARRIER();

#pragma unroll 2
  for (int t = 0; t < NT; ++t) {
    const int bo = (t & 1) * 65536;
    const int bno = bo ^ 65536;
    bf16x8 b0[4], b1[4];

    // ---------------- phase 0: B(all) + A frags 0,1; stage A-h0(t+1) ----------------
    {
      bf16x8 A0 = RD(bo + rowA0 + cs0);
      bf16x8 A1 = RD(bo + rowA0 + cs1);
      bf16x8 A0b = RD(bo + rowA0 + 2048 + cs0);
      bf16x8 A1b = RD(bo + rowA0 + 2048 + cs1);
#pragma unroll
      for (int nf = 0; nf < 4; ++nf) {
        b0[nf] = RD(bo + rowB0 + nf * 2048 + cs0);
        b1[nf] = RD(bo + rowB0 + nf * 2048 + cs1);
      }
      if (t + 1 < NT) STAGE(Ap, (t + 1) * BK, 0, bno + 0);
      BARRIER();
      asm volatile("s_waitcnt lgkmcnt(0)" ::: "memory");
      __builtin_amdgcn_s_setprio(1);
      MFMA4(0, A0, A1, b0, b1);
      __builtin_amdgcn_s_setprio(0);
      BARRIER();
    }
    // ---------------- phase 1: A frags 2,3; stage A-h1(t+1) ----------------
    {
      bf16x8 A0 = RD(bo + rowA0 + 4096 + cs0);
      bf16x8 A1 = RD(bo + rowA0 + 4096 + cs1);
      bf16x8 A0b = RD(bo + rowA0 + 6144 + cs0);
      bf16x8 A1b = RD(bo + rowA0 + 6144 + cs1);
      if (t + 1 < NT) STAGE(Ap, (t + 1) * BK, 128, bno + 16384);
      BARRIER();
      asm volatile("s_waitcnt lgkmcnt(0)" ::: "memory");
      __builtin_amdgcn_s_setprio(1);
      MFMA4(1, A0, A1, b0, b1);
      __builtin_amdgcn_s_setprio(0);
      BARRIER();
    }
    // ---------------- phase 2: A frags 4,5; stage B-h0(t+2) ----------------
    {
      bf16x8 A0 = RD(bo + rowA0 + 8192 + cs0);
      bf16x8 A1 = RD(bo + rowA0 + 8192 + cs1);
      bf16x8 A0b = RD(bo + rowA0 + 10240 + cs0);
      bf16x8 A1b = RD(bo + rowA0 + 10240 + cs1);
      if (t + 2 < NT) STAGE(Bp, (t + 2) * BK, 0, bo + 32768);
      BARRIER();
      asm volatile("s_waitcnt lgkmcnt(0)" ::: "memory");
      __builtin_amdgcn_s_setprio(1);
      MFMA4(2, A0, A1, b0, b1);
      __builtin_amdgcn_s_setprio(0);
      BARRIER();
    }
    // ---------------- phase 3: A frags 6,7; stage B-h1(t+2); boundary vmcnt ----------------
    {
      bf16x8 A0 = RD(bo + rowA0 + 12288 + cs0);
      bf16x8 A1 = RD(bo + rowA0 + 12288 + cs1);
      bf16x8 A0b = RD(bo + rowA0 + 14336 + cs0);
      bf16x8 A1b = RD(bo + rowA0 + 14336 + cs1);
      if (t + 2 < NT) STAGE(Bp, (t + 2) * BK, 128, bo + 49152);
      BARRIER();
      asm volatile("s_waitcnt lgkmcnt(0)" ::: "memory");
      __builtin_amdgcn_s_setprio(1);
      MFMA4(3, A0, A1, b0, b1);
      __builtin_amdgcn_s_setprio(0);
      if (t + 2 < NT) {
        asm volatile("s_waitcnt vmcnt(4)" ::: "memory");
      } else {
        asm volatile("s_waitcnt vmcnt(0)" ::: "memory");
      }
      BARRIER();
    }
  }

  // ---- epilogue: C = acc + bias ----
  const int lg4 = (lane >> 4) << 2;
#pragma unroll
  for (int nf = 0; nf < 4; ++nf) {
    const int col = bn * BN + wn * 64 + nf * 16 + lr;
    const float bv = bias[col];
#pragma unroll
    for (int mf = 0; mf < 8; ++mf) {
      const int row0 = bm * BM + wm * 128 + mf * 16 + lg4;
      float* cp = C + (size_t)row0 * N_TOT + col;
#pragma unroll
      for (int j = 0; j < 4; ++j) cp[(size_t)j * N_TOT] = acc[mf][nf][j] + bv;
    }
  }
#undef RD
#undef STAGE
#undef BARRIER
#undef MFMA4
}

extern "C" void kernel_launch(void* const* d_in, const int* in_sizes, int n_in,
                              void* d_out, int out_size, void* d_ws, size_t ws_size,
                              hipStream_t stream) {
  const float* x    = (const float*)d_in[0];   // [4,2048,4096] f32
  const float* cb   = (const float*)d_in[1];   // [4096,256]   f32
  const float* bias = (const float*)d_in[2];   // [4096]       f32
  const int*   idx  = (const int*)d_in[3];     // [4096,4096]  int

  float* out = (float*)d_out;                  // [4,2048,4096] f32

  unsigned short* Wb = (unsigned short*)d_ws;                                      // 32 MB
  unsigned short* Xc = (unsigned short*)((char*)d_ws + (size_t)N_TOT * K_TOT * 2); // 64 MB

  deq_w<<<(N_TOT * (size_t)K_TOT) / (8 * 256), 256, 0, stream>>>(cb, idx, Wb);
  conv_x<<<((size_t)M_TOT * K_TOT) / (8 * 256), 256, 0, stream>>>(x, Xc);
  // (8192/256) * (4096/256) = 32*16 = 512 blocks, 512 threads
  gemm8<<<512, 512, 0, stream>>>(Xc, Wb, bias, out);
}

// Round 3
// 274.192 us; speedup vs baseline: 1.3968x; 1.0518x over previous
//
#include <hip/hip_runtime.h>

typedef __bf16 bf16x8 __attribute__((ext_vector_type(8)));
typedef float f32x4 __attribute__((ext_vector_type(4)));
typedef unsigned short u16x8 __attribute__((ext_vector_type(8)));
typedef int i32x4 __attribute__((ext_vector_type(4)));

#define M_TOT 8192
#define K_TOT 4096
#define N_TOT 4096
#define BM 256
#define BN 256
#define BK 64
#define NT (K_TOT / BK)   // 64

__device__ __forceinline__ unsigned short f2bf(float f) {
  union { float f; unsigned int u; } v; v.f = f;
  unsigned int u = v.u;
  return (unsigned short)((u + 0x7FFFu + ((u >> 16) & 1u)) >> 16);  // RNE
}

// weight[o][i] = bf16(codebook[o, indices[o,i]]); one thread = 8 contiguous elems
__global__ __launch_bounds__(256) void deq_w(const float* __restrict__ cb,
                                             const int* __restrict__ idx,
                                             unsigned short* __restrict__ Wb) {
  size_t base = ((size_t)blockIdx.x * 256 + threadIdx.x) * 8;
  const float* crow = cb + ((base >> 12) << 8);  // row = base/4096, 256 floats/row
  i32x4 i0 = *(const i32x4*)(idx + base);
  i32x4 i1 = *(const i32x4*)(idx + base + 4);
  u16x8 o;
#pragma unroll
  for (int j = 0; j < 4; ++j) { o[j] = f2bf(crow[i0[j]]); o[4 + j] = f2bf(crow[i1[j]]); }
  *(u16x8*)(Wb + base) = o;
}

// x f32 -> bf16
__global__ __launch_bounds__(256) void conv_x(const float* __restrict__ X,
                                              unsigned short* __restrict__ Xc) {
  size_t base = ((size_t)blockIdx.x * 256 + threadIdx.x) * 8;
  f32x4 a = *(const f32x4*)(X + base);
  f32x4 b = *(const f32x4*)(X + base + 4);
  u16x8 o;
#pragma unroll
  for (int j = 0; j < 4; ++j) { o[j] = f2bf(a[j]); o[4 + j] = f2bf(b[j]); }
  *(u16x8*)(Xc + base) = o;
}

#define GLDS16(g, l)                                                      \
  __builtin_amdgcn_global_load_lds(                                       \
      (__attribute__((address_space(1))) void*)(g),                       \
      (__attribute__((address_space(3))) void*)(l), 16, 0, 0)

// ============================================================================
// 256x256 tile, BK=64, 8 waves (2M x 4N), double-buffered 128KB LDS,
// 4 phases per K-tile. Balanced ds_reads (8/4/6/6 per phase) via B register
// pipelining: B(t+1) nf=0,1 prefetched to regs at tile t p2/p3 (other buf);
// nf=2,3 read at p0 of the consuming tile. Counted vmcnt(4) at p1-end
// (retires B(t+1) ahead of its reg-prefetch) and at tile boundary (retires
// A(t+1)); waits precede barriers so cross-wave landing is guaranteed.
// Stages: p0 A(t+1)h0, p1 A(t+1)h1, p2 B(t+2)h0, p3 B(t+2)h1.
// ============================================================================
__global__ __launch_bounds__(512, 2) void gemm8(const unsigned short* __restrict__ A,
                                                const unsigned short* __restrict__ B,
                                                const float* __restrict__ bias,
                                                float* __restrict__ C) {
  __shared__ __attribute__((aligned(128))) char lds[131072];

  const int tid = threadIdx.x;
  const int lane = tid & 63;
  const int wm = (tid >> 6) >> 2;   // 0..1
  const int wn = (tid >> 6) & 3;    // 0..3
  const int lr = lane & 15;

  const int bid = blockIdx.x;                    // nwg = 512 = 8 * 64, bijective
  const int swz = (bid & 7) * 64 + (bid >> 3);
  const int bm = swz >> 4;                       // 0..31
  const int bn = swz & 15;                       // 0..15

  const unsigned short* Ap = A + (size_t)bm * BM * K_TOT;
  const unsigned short* Bp = B + (size_t)bn * BN * K_TOT;

  // staging: 512 thr x 16B = 64 rows/issue, 2 issues per 128-row half
  const int srow = tid >> 3;                              // 0..63
  const int sgcol = (((tid & 7) * 16) ^ ((srow & 7) << 4)) >> 1;  // elem col (inv swizzle)
  const int wavebase = (tid & 448) << 4;                  // wave-uniform LDS base part

  // fragment-read constants (swizzled byte cols for k-halves 0/1)
  const int cs0 = (((lane >> 4) << 4)) ^ ((lr & 7) << 4);
  const int cs1 = (64 + ((lane >> 4) << 4)) ^ ((lr & 7) << 4);
  const int rowA0 = (wm * 128 + lr) * 128;          // byte base of A frags
  const int rowB0 = 32768 + (wn * 64 + lr) * 128;   // byte base of B frags

#define RD(off) (*(const bf16x8*)(lds + (off)))
#define STAGE(GB, TK, RB, LOFF)                                               \
  { _Pragma("unroll")                                                         \
    for (int ii = 0; ii < 2; ++ii) {                                          \
      GLDS16((GB) + (size_t)((RB) + ii * 64 + srow) * K_TOT + (TK) + sgcol,   \
             lds + (LOFF) + ii * 8192 + wavebase);                            \
    } }
#define BARRIER()                       \
  {                                     \
    asm volatile("" ::: "memory");      \
    __builtin_amdgcn_s_barrier();       \
    asm volatile("" ::: "memory");      \
  }
#define LGKM0() asm volatile("s_waitcnt lgkmcnt(0)" ::: "memory")

// 16 MFMA: mf = 2P,2P+1 over nf=0..3, K=64 (k-halves). B: nf0,1 from BPC regs
// (prefetched last tile), nf2,3 from bT regs (read at p0 this tile).
#define MFMA_PH(P, BPC)                                                                  \
  { _Pragma("unroll")                                                                    \
    for (int nf = 0; nf < 4; ++nf) {                                                     \
      bf16x8 Bk0 = (nf == 0) ? BPC[0] : (nf == 1) ? BPC[2] : (nf == 2) ? bT0 : bT2;      \
      bf16x8 Bk1 = (nf == 0) ? BPC[1] : (nf == 1) ? BPC[3] : (nf == 2) ? bT1 : bT3;      \
      acc[2*(P)][nf]   = __builtin_amdgcn_mfma_f32_16x16x32_bf16(A0,  Bk0, acc[2*(P)][nf],   0, 0, 0); \
      acc[2*(P)][nf]   = __builtin_amdgcn_mfma_f32_16x16x32_bf16(A1,  Bk1, acc[2*(P)][nf],   0, 0, 0); \
      acc[2*(P)+1][nf] = __builtin_amdgcn_mfma_f32_16x16x32_bf16(A0b, Bk0, acc[2*(P)+1][nf], 0, 0, 0); \
      acc[2*(P)+1][nf] = __builtin_amdgcn_mfma_f32_16x16x32_bf16(A1b, Bk1, acc[2*(P)+1][nf], 0, 0, 0); \
    } }

// One K-tile: T = tile idx, BO = its LDS buffer byte offset, BPC = B regs for
// this tile (nf0,1), BPN = B regs to fill for tile T+1. Flags compile-time.
#define TILE(T, BO, BPC, BPN, STG_A, STG_B, RD_BPN, VMF)                      \
  {                                                                           \
    /* ---- phase 0: A mf0,1 + B nf2,3 (8 reads); stage A(T+1)h0 ---- */      \
    bf16x8 A0  = RD((BO) + rowA0 + cs0);                                      \
    bf16x8 A1  = RD((BO) + rowA0 + cs1);                                      \
    bf16x8 A0b = RD((BO) + rowA0 + 2048 + cs0);                               \
    bf16x8 A1b = RD((BO) + rowA0 + 2048 + cs1);                               \
    bf16x8 bT0 = RD((BO) + rowB0 + 4096 + cs0);                               \
    bf16x8 bT1 = RD((BO) + rowB0 + 4096 + cs1);                               \
    bf16x8 bT2 = RD((BO) + rowB0 + 6144 + cs0);                               \
    bf16x8 bT3 = RD((BO) + rowB0 + 6144 + cs1);                               \
    if (STG_A) STAGE(Ap, ((T) + 1) * BK, 0, ((BO) ^ 65536) + 0);              \
    BARRIER();                                                                \
    LGKM0();                                                                  \
    __builtin_amdgcn_s_setprio(1);                                            \
    MFMA_PH(0, BPC);                                                          \
    __builtin_amdgcn_s_setprio(0);                                            \
    BARRIER();                                                                \
    /* ---- phase 1: A mf2,3 (4 reads); stage A(T+1)h1; vmcnt(4) ---- */      \
    A0  = RD((BO) + rowA0 + 4096 + cs0);                                      \
    A1  = RD((BO) + rowA0 + 4096 + cs1);                                      \
    A0b = RD((BO) + rowA0 + 6144 + cs0);                                      \
    A1b = RD((BO) + rowA0 + 6144 + cs1);                                      \
    if (STG_A) STAGE(Ap, ((T) + 1) * BK, 128, ((BO) ^ 65536) + 16384);        \
    BARRIER();                                                                \
    LGKM0();                                                                  \
    __builtin_amdgcn_s_setprio(1);                                            \
    MFMA_PH(1, BPC);                                                          \
    __builtin_amdgcn_s_setprio(0);                                            \
    if (RD_BPN) { asm volatile("s_waitcnt vmcnt(4)" ::: "memory"); }          \
    BARRIER();                                                                \
    /* ---- phase 2: A mf4,5 + BPN nf0 (6 reads); stage B(T+2)h0 ---- */      \
    A0  = RD((BO) + rowA0 + 8192 + cs0);                                      \
    A1  = RD((BO) + rowA0 + 8192 + cs1);                                      \
    A0b = RD((BO) + rowA0 + 10240 + cs0);                                     \
    A1b = RD((BO) + rowA0 + 10240 + cs1);                                     \
    if (RD_BPN) {                                                             \
      BPN[0] = RD(((BO) ^ 65536) + rowB0 + cs0);                              \
      BPN[1] = RD(((BO) ^ 65536) + rowB0 + cs1);                              \
    }                                                                         \
    if (STG_B) STAGE(Bp, ((T) + 2) * BK, 0, (BO) + 32768);                    \
    BARRIER();                                                                \
    LGKM0();                                                                  \
    __builtin_amdgcn_s_setprio(1);                                            \
    MFMA_PH(2, BPC);                                                          \
    __builtin_amdgcn_s_setprio(0);                                            \
    BARRIER();                                                                \
    /* ---- phase 3: A mf6,7 + BPN nf1 (6 reads); stage B(T+2)h1 ---- */      \
    A0  = RD((BO) + rowA0 + 12288 + cs0);                                     \
    A1  = RD((BO) + rowA0 + 12288 + cs1);                                     \
    A0b = RD((BO) + rowA0 + 14336 + cs0);                                     \
    A1b = RD((BO) + rowA0 + 14336 + cs1);                                     \
    if (RD_BPN) {                                                             \
      BPN[2] = RD(((BO) ^ 65536) + rowB0 + 2048 + cs0);                       \
      BPN[3] = RD(((BO) ^ 65536) + rowB0 + 2048 + cs1);                       \
    }                                                                         \
    if (STG_B) STAGE(Bp, ((T) + 2) * BK, 128, (BO) + 49152);                  \
    BARRIER();                                                                \
    LGKM0();                                                                  \
    __builtin_amdgcn_s_setprio(1);                                            \
    MFMA_PH(3, BPC);                                                          \
    __builtin_amdgcn_s_setprio(0);                                            \
    asm volatile("s_waitcnt vmcnt(" VMF ")" ::: "memory");                    \
    BARRIER();                                                                \
  }

  f32x4 acc[8][4] = {};
  bf16x8 bPA[4], bPB[4];

  // ---- prologue: stage B(0), A(0), B(1); read B(0) nf0,1 into bPA ----
  STAGE(Bp, 0, 0, 32768);
  STAGE(Bp, 0, 128, 49152);
  STAGE(Ap, 0, 0, 0);
  STAGE(Ap, 0, 128, 16384);
  STAGE(Bp, BK, 0, 65536 + 32768);
  STAGE(Bp, BK, 128, 65536 + 49152);
  asm volatile("s_waitcnt vmcnt(8)" ::: "memory");   // B(0) landed (all waves after barrier)
  BARRIER();
  bPA[0] = RD(rowB0 + cs0);
  bPA[1] = RD(rowB0 + cs1);
  bPA[2] = RD(rowB0 + 2048 + cs0);
  bPA[3] = RD(rowB0 + 2048 + cs1);
  asm volatile("s_waitcnt vmcnt(4)" ::: "memory");   // A(0) landed; B(1) in flight
  BARRIER();

  // main loop: tiles 0..NT-3 fully pipelined; tiles NT-2, NT-1 specialized
  for (int t = 0; t < NT - 2; t += 2) {
    TILE(t,     0,     bPA, bPB, 1, 1, 1, "4");
    TILE(t + 1, 65536, bPB, bPA, 1, 1, 1, "4");
  }
  TILE(NT - 2, 0,     bPA, bPB, 1, 0, 1, "0");
  TILE(NT - 1, 65536, bPB, bPA, 0, 0, 0, "0");

  // ---- epilogue: C = acc + bias ----
  const int lg4 = (lane >> 4) << 2;
#pragma unroll
  for (int nf = 0; nf < 4; ++nf) {
    const int col = bn * BN + wn * 64 + nf * 16 + lr;
    const float bv = bias[col];
#pragma unroll
    for (int mf = 0; mf < 8; ++mf) {
      const int row0 = bm * BM + wm * 128 + mf * 16 + lg4;
      float* cp = C + (size_t)row0 * N_TOT + col;
#pragma unroll
      for (int j = 0; j < 4; ++j) cp[(size_t)j * N_TOT] = acc[mf][nf][j] + bv;
    }
  }
#undef RD
#undef STAGE
#undef BARRIER
#undef LGKM0
#undef MFMA_PH
#undef TILE
}

extern "C" void kernel_launch(void* const* d_in, const int* in_sizes, int n_in,
                              void* d_out, int out_size, void* d_ws, size_t ws_size,
                              hipStream_t stream) {
  const float* x    = (const float*)d_in[0];   // [4,2048,4096] f32
  const float* cb   = (const float*)d_in[1];   // [4096,256]   f32
  const float* bias = (const float*)d_in[2];   // [4096]       f32
  const int*   idx  = (const int*)d_in[3];     // [4096,4096]  int

  float* out = (float*)d_out;                  // [4,2048,4096] f32

  unsigned short* Wb = (unsigned short*)d_ws;                                      // 32 MB
  unsigned short* Xc = (unsigned short*)((char*)d_ws + (size_t)N_TOT * K_TOT * 2); // 64 MB

  deq_w<<<(N_TOT * (size_t)K_TOT) / (8 * 256), 256, 0, stream>>>(cb, idx, Wb);
  conv_x<<<((size_t)M_TOT * K_TOT) / (8 * 256), 256, 0, stream>>>(x, Xc);
  // (8192/256) * (4096/256) = 32*16 = 512 blocks, 512 threads
  gemm8<<<512, 512, 0, stream>>>(Xc, Wb, bias, out);
}

// Round 4
// 274.144 us; speedup vs baseline: 1.3970x; 1.0002x over previous
//
#include <hip/hip_runtime.h>

typedef __bf16 bf16x8 __attribute__((ext_vector_type(8)));
typedef float f32x4 __attribute__((ext_vector_type(4)));
typedef unsigned short u16x8 __attribute__((ext_vector_type(8)));
typedef int i32x4 __attribute__((ext_vector_type(4)));

#define M_TOT 8192
#define K_TOT 4096
#define N_TOT 4096
#define BM 256
#define BN 256
#define BK 64
#define NT (K_TOT / BK)   // 64

__device__ __forceinline__ unsigned short f2bf(float f) {
  union { float f; unsigned int u; } v; v.f = f;
  unsigned int u = v.u;
  return (unsigned short)((u + 0x7FFFu + ((u >> 16) & 1u)) >> 16);  // RNE
}

// weight[o][i] = bf16(codebook[o, indices[o,i]]); one thread = 8 contiguous elems
__global__ __launch_bounds__(256) void deq_w(const float* __restrict__ cb,
                                             const int* __restrict__ idx,
                                             unsigned short* __restrict__ Wb) {
  size_t base = ((size_t)blockIdx.x * 256 + threadIdx.x) * 8;
  const float* crow = cb + ((base >> 12) << 8);  // row = base/4096, 256 floats/row
  i32x4 i0 = *(const i32x4*)(idx + base);
  i32x4 i1 = *(const i32x4*)(idx + base + 4);
  u16x8 o;
#pragma unroll
  for (int j = 0; j < 4; ++j) { o[j] = f2bf(crow[i0[j]]); o[4 + j] = f2bf(crow[i1[j]]); }
  *(u16x8*)(Wb + base) = o;
}

// x f32 -> bf16
__global__ __launch_bounds__(256) void conv_x(const float* __restrict__ X,
                                              unsigned short* __restrict__ Xc) {
  size_t base = ((size_t)blockIdx.x * 256 + threadIdx.x) * 8;
  f32x4 a = *(const f32x4*)(X + base);
  f32x4 b = *(const f32x4*)(X + base + 4);
  u16x8 o;
#pragma unroll
  for (int j = 0; j < 4; ++j) { o[j] = f2bf(a[j]); o[4 + j] = f2bf(b[j]); }
  *(u16x8*)(Xc + base) = o;
}

#define GLDS16(g, l)                                                      \
  __builtin_amdgcn_global_load_lds(                                       \
      (__attribute__((address_space(1))) void*)(g),                       \
      (__attribute__((address_space(3))) void*)(l), 16, 0, 0)

// ============================================================================
// 256x256 tile, BK=64, 8 waves (2M x 4N), double-buffered 128KB LDS.
// TWO barriers per K-tile (was 8): ds_reads pipelined under MFMA at register
// level; compiler inserts counted lgkm waits for operand deps.
// Quadrant phases (m-half x k-half), 16 MFMA each:
//   p0 = (mh0,kh0): Aa x Bx    p1 = (mh1,kh0): Ab x Bx
//   p2 = (mh0,kh1): Ac x By    p3 = (mh1,kh1): Ad x By
// Reads for p+1 issued before MFMA of p. Mid-tile lgkmcnt(0)+barrier makes
// all waves' B(t) LDS reads complete -> staging B(t+2) into current B region
// is race-free. Ad read after mid-barrier (keeps lgkm0 cheap+reorder-robust).
// End-of-tile: counted vmcnt(4) (retires A(t+1),B(t+1); leaves B(t+2) in
// flight) + barrier. Stages per tile t: A(t+1) h0,h1 early; B(t+2) h0,h1
// after mid-barrier.
// ============================================================================
__global__ __launch_bounds__(512, 2) void gemm8(const unsigned short* __restrict__ A,
                                                const unsigned short* __restrict__ B,
                                                const float* __restrict__ bias,
                                                float* __restrict__ C) {
  __shared__ __attribute__((aligned(128))) char lds[131072];

  const int tid = threadIdx.x;
  const int lane = tid & 63;
  const int wm = (tid >> 6) >> 2;   // 0..1
  const int wn = (tid >> 6) & 3;    // 0..3
  const int lr = lane & 15;

  const int bid = blockIdx.x;                    // nwg = 512 = 8 * 64, bijective
  const int swz = (bid & 7) * 64 + (bid >> 3);
  const int bm = swz >> 4;                       // 0..31
  const int bn = swz & 15;                       // 0..15

  const unsigned short* Ap = A + (size_t)bm * BM * K_TOT;
  const unsigned short* Bp = B + (size_t)bn * BN * K_TOT;

  // staging: 512 thr x 16B = 64 rows/issue, 2 issues per 128-row half
  const int srow = tid >> 3;                              // 0..63
  const int sgcol = (((tid & 7) * 16) ^ ((srow & 7) << 4)) >> 1;  // elem col (inv swizzle)
  const int wavebase = (tid & 448) << 4;                  // wave-uniform LDS base part

  // fragment-read constants (swizzled byte cols for k-halves 0/1)
  const int cs0 = (((lane >> 4) << 4)) ^ ((lr & 7) << 4);
  const int cs1 = (64 + ((lane >> 4) << 4)) ^ ((lr & 7) << 4);
  const int rowA0 = (wm * 128 + lr) * 128;          // byte base of A frags
  const int rowB0 = 32768 + (wn * 64 + lr) * 128;   // byte base of B frags

#define RD(off) (*(const bf16x8*)(lds + (off)))
#define STAGE(GB, TK, RB, LOFF)                                               \
  { _Pragma("unroll")                                                         \
    for (int ii = 0; ii < 2; ++ii) {                                          \
      GLDS16((GB) + (size_t)((RB) + ii * 64 + srow) * K_TOT + (TK) + sgcol,   \
             lds + (LOFF) + ii * 8192 + wavebase);                            \
    } }
#define BARRIER()                       \
  {                                     \
    asm volatile("" ::: "memory");      \
    __builtin_amdgcn_s_barrier();       \
    asm volatile("" ::: "memory");      \
  }

// 16 MFMA for quadrant (m-half MH, one k-half): 4 A-frags x 4 B-frags
#define MFMA_Q(MH, AV, BV)                                                    \
  { __builtin_amdgcn_s_setprio(1);                                            \
    _Pragma("unroll")                                                         \
    for (int r = 0; r < 4; ++r) {                                             \
      _Pragma("unroll")                                                       \
      for (int nf = 0; nf < 4; ++nf)                                          \
        acc[(MH) * 4 + r][nf] = __builtin_amdgcn_mfma_f32_16x16x32_bf16(      \
            AV[r], BV[nf], acc[(MH) * 4 + r][nf], 0, 0, 0);                   \
    }                                                                         \
    __builtin_amdgcn_s_setprio(0); }

#define TILE(T, BO, STG_A, STG_B, VMF, DO_BAR)                                    \
  {                                                                               \
    bf16x8 Aa[4], Ab[4], Ac[4], Ad[4], Bx[4], By[4];                              \
    _Pragma("unroll") for (int r = 0; r < 4; ++r)                                 \
        Aa[r] = RD((BO) + rowA0 + r * 2048 + cs0);                                \
    _Pragma("unroll") for (int n = 0; n < 4; ++n)                                 \
        Bx[n] = RD((BO) + rowB0 + n * 2048 + cs0);                                \
    if (STG_A) STAGE(Ap, ((T) + 1) * BK, 0, ((BO) ^ 65536) + 0);                  \
    _Pragma("unroll") for (int r = 0; r < 4; ++r)                                 \
        Ab[r] = RD((BO) + rowA0 + (4 + r) * 2048 + cs0);                          \
    if (STG_A) STAGE(Ap, ((T) + 1) * BK, 128, ((BO) ^ 65536) + 16384);            \
    MFMA_Q(0, Aa, Bx);                                                            \
    _Pragma("unroll") for (int r = 0; r < 4; ++r)                                 \
        Ac[r] = RD((BO) + rowA0 + r * 2048 + cs1);                                \
    _Pragma("unroll") for (int n = 0; n < 4; ++n)                                 \
        By[n] = RD((BO) + rowB0 + n * 2048 + cs1);                                \
    MFMA_Q(1, Ab, Bx);                                                            \
    asm volatile("s_waitcnt lgkmcnt(0)" ::: "memory");                            \
    BARRIER();                                                                    \
    if (STG_B) STAGE(Bp, ((T) + 2) * BK, 0, (BO) + 32768);                        \
    if (STG_B) STAGE(Bp, ((T) + 2) * BK, 128, (BO) + 49152);                      \
    _Pragma("unroll") for (int r = 0; r < 4; ++r)                                 \
        Ad[r] = RD((BO) + rowA0 + (4 + r) * 2048 + cs1);                          \
    MFMA_Q(0, Ac, By);                                                            \
    MFMA_Q(1, Ad, By);                                                            \
    asm volatile("s_waitcnt vmcnt(" VMF ")" ::: "memory");                        \
    if (DO_BAR) BARRIER();                                                        \
  }

  f32x4 acc[8][4] = {};

  // ---- prologue: stage B(0), A(0), B(1); wait B0+A0 landed (B1 in flight) ----
  STAGE(Bp, 0, 0, 32768);
  STAGE(Bp, 0, 128, 49152);
  STAGE(Ap, 0, 0, 0);
  STAGE(Ap, 0, 128, 16384);
  STAGE(Bp, BK, 0, 65536 + 32768);
  STAGE(Bp, BK, 128, 65536 + 49152);
  asm volatile("s_waitcnt vmcnt(4)" ::: "memory");
  BARRIER();

  // main loop: tiles 0..NT-3 fully pipelined; last two tiles specialized
  for (int t = 0; t < NT - 2; t += 2) {
    TILE(t,     0,     1, 1, "4", 1);
    TILE(t + 1, 65536, 1, 1, "4", 1);
  }
  TILE(NT - 2, 0,     1, 0, "0", 1);
  TILE(NT - 1, 65536, 0, 0, "0", 0);

  // ---- epilogue: C = acc + bias ----
  const int lg4 = (lane >> 4) << 2;
#pragma unroll
  for (int nf = 0; nf < 4; ++nf) {
    const int col = bn * BN + wn * 64 + nf * 16 + lr;
    const float bv = bias[col];
#pragma unroll
    for (int mf = 0; mf < 8; ++mf) {
      const int row0 = bm * BM + wm * 128 + mf * 16 + lg4;
      float* cp = C + (size_t)row0 * N_TOT + col;
#pragma unroll
      for (int j = 0; j < 4; ++j) cp[(size_t)j * N_TOT] = acc[mf][nf][j] + bv;
    }
  }
#undef RD
#undef STAGE
#undef BARRIER
#undef MFMA_Q
#undef TILE
}

extern "C" void kernel_launch(void* const* d_in, const int* in_sizes, int n_in,
                              void* d_out, int out_size, void* d_ws, size_t ws_size,
                              hipStream_t stream) {
  const float* x    = (const float*)d_in[0];   // [4,2048,4096] f32
  const float* cb   = (const float*)d_in[1];   // [4096,256]   f32
  const float* bias = (const float*)d_in[2];   // [4096]       f32
  const int*   idx  = (const int*)d_in[3];     // [4096,4096]  int

  float* out = (float*)d_out;                  // [4,2048,4096] f32

  unsigned short* Wb = (unsigned short*)d_ws;                                      // 32 MB
  unsigned short* Xc = (unsigned short*)((char*)d_ws + (size_t)N_TOT * K_TOT * 2); // 64 MB

  deq_w<<<(N_TOT * (size_t)K_TOT) / (8 * 256), 256, 0, stream>>>(cb, idx, Wb);
  conv_x<<<((size_t)M_TOT * K_TOT) / (8 * 256), 256, 0, stream>>>(x, Xc);
  // (8192/256) * (4096/256) = 32*16 = 512 blocks, 512 threads
  gemm8<<<512, 512, 0, stream>>>(Xc, Wb, bias, out);
}